// Round 12
// baseline (186.342 us; speedup 1.0000x reference)
//
#include <hip/hip_runtime.h>
#include <math.h>

#define LSEQ 1024
#define NB 16
#define NC 12
#define NH 256
#define NM 32
#define NS 3
#define TWO_PI 6.283185307179586f

#define NPL   8          // split-K planes
#define PSTR  196608     // P plane stride (3*256*256)
#define VPSTR 786432     // V plane stride (3*256*1024)

// ---- workspace layout (float offsets) ----
#define OFF_MEANS 0            // 192
#define OFF_STDEV 192          // 192
#define OFF_EPART 384          // 24576
#define OFF_WT_RE 24960        // 24576
#define OFF_WT_IM 49536        // 24576
#define OFF_VP    74112        // 8 planes x 786432 = 6291456
#define OFF_V     6365568      // 786432 (dense; only cols 0..511 used)
#define OFF_PP0   7152000      // 8 planes x 196608 = 1572864
#define OFF_PP1   8724864      // 1572864
#define OFF_H     10297728     // 1024
#define OFF_Z9R   10298752     // 24576
#define OFF_Z9I   10323328     // 24576
// total ~10.35M floats = 41.4 MB

__device__ __forceinline__ float block_reduce_sum(float v, float* sbuf) {
  int t = threadIdx.x;
  sbuf[t] = v; __syncthreads();
  for (int off = 128; off > 0; off >>= 1) {
    if (t < off) sbuf[t] += sbuf[t + off];
    __syncthreads();
  }
  float r = sbuf[0];
  __syncthreads();
  return r;
}

// float4 wtilde task for one (s,i): wt[s,k,i] = sum_o ebar[s,o]*w[s,i,o,k]
__device__ __forceinline__ void wtilde_task(int w, float* smem,
                                            const float* __restrict__ wre,
                                            const float* __restrict__ wim,
                                            const float* __restrict__ epart,
                                            float* __restrict__ wt_re,
                                            float* __restrict__ wt_im) {
  int s = w >> 8, i = w & 255;
  int t = threadIdx.x;
  float* ebs = smem;
  float* sr  = smem + 256;
  float* si2 = smem + 1280;
  float eb = 0.f;
  for (int ch = 0; ch < 32; ++ch) eb += epart[(s * 32 + ch) * 256 + t];
  ebs[t] = eb * (1.0f / LSEQ);
  __syncthreads();
  const float* br = wre + (size_t)(s * NH + i) * NH * NM;
  const float* bi = wim + (size_t)(s * NH + i) * NH * NM;
  float aR[4] = {0.f, 0.f, 0.f, 0.f}, aI[4] = {0.f, 0.f, 0.f, 0.f};
  #pragma unroll
  for (int it = 0; it < 8; ++it) {
    int o = (t >> 3) + 32 * it;
    float e = ebs[o];
    float4 vr = *(const float4*)(br + (size_t)t * 4 + 1024 * it);
    float4 vi = *(const float4*)(bi + (size_t)t * 4 + 1024 * it);
    aR[0] += e * vr.x; aR[1] += e * vr.y; aR[2] += e * vr.z; aR[3] += e * vr.w;
    aI[0] += e * vi.x; aI[1] += e * vi.y; aI[2] += e * vi.z; aI[3] += e * vi.w;
  }
  *(float4*)(sr + t * 4)  = make_float4(aR[0], aR[1], aR[2], aR[3]);
  *(float4*)(si2 + t * 4) = make_float4(aI[0], aI[1], aI[2], aI[3]);
  __syncthreads();
  if (t < 32) {
    float r = 0.f, im = 0.f;
    #pragma unroll
    for (int og = 0; og < 32; ++og) { r += sr[og * 32 + t]; im += si2[og * 32 + t]; }
    wt_re[(size_t)(s * NM + t) * NH + i] = r;
    wt_im[(size_t)(s * NM + t) * NH + i] = im;
  }
  __syncthreads();
}

#define FMA_ROW(r, av) { acc[r][0] += (av)*b4.x; acc[r][1] += (av)*b4.y; acc[r][2] += (av)*b4.z; acc[r][3] += (av)*b4.w; }

// 128x64 output tile, single K-slice of 32 (one barrier round). 8x4 acc/thread.
template<int ANP, int BNP>
__device__ __forceinline__ void gemm32(float* As, float* Bs,
                       const float* Abase, int apstr,
                       const float* Bbase, int bpstr, int bld, int colLimit,
                       int rowbase, int colbase, int kb,
                       float* outp, int outld, int outcol0, int outColLim) {
  const int tid = threadIdx.x;
  const int tx = tid & 15, ty = tid >> 4;
  const int kkA = tid & 31, rA = tid >> 5;
  const int jB = tid & 63, kB = tid >> 6;
  float acc[8][4];
  #pragma unroll
  for (int i = 0; i < 8; ++i)
    #pragma unroll
    for (int j = 0; j < 4; ++j) acc[i][j] = 0.f;

  #pragma unroll
  for (int p = 0; p < 16; ++p) {
    int row = rowbase + rA + 8 * p;
    float pv[ANP];
    #pragma unroll
    for (int pp = 0; pp < ANP; ++pp)
      pv[pp] = Abase[(size_t)pp * apstr + (size_t)row * 256 + kb + kkA];
    float v = pv[0];
    #pragma unroll
    for (int pp = 1; pp < ANP; ++pp) v += pv[pp];
    As[kkA * 132 + rA + 8 * p] = v;
  }
  #pragma unroll
  for (int q = 0; q < 8; ++q) {
    int kk = kB + 4 * q;
    int j = colbase + jB;
    float v = 0.f;
    if (j < colLimit) {
      float pv[BNP];
      #pragma unroll
      for (int pp = 0; pp < BNP; ++pp)
        pv[pp] = Bbase[(size_t)pp * bpstr + (size_t)(kb + kk) * bld + j];
      v = pv[0];
      #pragma unroll
      for (int pp = 1; pp < BNP; ++pp) v += pv[pp];
    }
    Bs[kk * 68 + jB] = v;
  }
  __syncthreads();
  #pragma unroll
  for (int kk = 0; kk < 32; ++kk) {
    float4 b4 = *(const float4*)(Bs + kk * 68 + tx * 4);
    float4 a0 = *(const float4*)(As + kk * 132 + ty * 8);
    float4 a1 = *(const float4*)(As + kk * 132 + ty * 8 + 4);
    FMA_ROW(0, a0.x) FMA_ROW(1, a0.y) FMA_ROW(2, a0.z) FMA_ROW(3, a0.w)
    FMA_ROW(4, a1.x) FMA_ROW(5, a1.y) FMA_ROW(6, a1.z) FMA_ROW(7, a1.w)
  }
  __syncthreads();
  if (colbase + 64 <= outColLim) {
    #pragma unroll
    for (int i = 0; i < 8; ++i) {
      int row = rowbase + ty * 8 + i;
      float4 st; st.x = acc[i][0]; st.y = acc[i][1]; st.z = acc[i][2]; st.w = acc[i][3];
      *(float4*)(outp + (size_t)row * outld + outcol0 + colbase + tx * 4) = st;
    }
  } else {
    #pragma unroll
    for (int i = 0; i < 8; ++i) {
      int row = rowbase + ty * 8 + i;
      #pragma unroll
      for (int j = 0; j < 4; ++j) {
        int c = colbase + tx * 4 + j;
        if (c < outColLim) outp[(size_t)row * outld + outcol0 + c] = acc[i][j];
      }
    }
  }
}

// chain stage: squares | extends | wtilde | stats | epart | V01 | H/out init
template<int ANP>
__global__ __launch_bounds__(256) void k_chain(const float* __restrict__ Pc,
                                               float* __restrict__ Pn,
                                               float* __restrict__ Vp,
                                               int m, int nSq, int ntct,
                                               const float* __restrict__ wre,
                                               const float* __restrict__ wim,
                                               const float* __restrict__ epart_c,
                                               float* __restrict__ wt_re,
                                               float* __restrict__ wt_im,
                                               int wstart, int wcount,
                                               const float* __restrict__ x,
                                               float* __restrict__ means,
                                               float* __restrict__ stdev,
                                               int statCount,
                                               const float* __restrict__ ev,
                                               float* __restrict__ epart_w,
                                               int epCount,
                                               const float* __restrict__ Bv,
                                               int v01Count,
                                               const float* __restrict__ b_fc,
                                               float* __restrict__ H,
                                               float* __restrict__ out,
                                               int hCount) {
  __shared__ float smem[6608];
  float* As = smem;            // [32][132]
  float* Bs = smem + 4224;     // [32][68]
  const int blk = blockIdx.x;
  const int t = threadIdx.x;
  const int nExt = 48 * ntct;
  const int b0 = nSq + nExt;
  const int b1 = b0 + wcount;
  const int b2 = b1 + statCount;
  const int b3 = b2 + epCount;
  const int b4_ = b3 + v01Count;
  if (blk < nSq) {
    int slice = blk & 7, rest = blk >> 3;
    int t8 = rest & 7, s = rest >> 3;
    int rt = t8 & 1, ct = t8 >> 1;
    const float* Ab = Pc + (size_t)s * 65536;
    gemm32<ANP, ANP>(As, Bs, Ab, PSTR, Ab, PSTR, 256, 256,
           rt * 128, ct * 64, slice * 32,
           Pn + (size_t)slice * PSTR + (size_t)s * 65536, 256, 0, 256);
  } else if (blk < b0) {
    int e = blk - nSq;
    int slice = e & 7, rt = (e >> 3) & 1, rest2 = e >> 4;
    int ct = rest2 % ntct, s = rest2 / ntct;
    gemm32<ANP, NPL>(As, Bs, Pc + (size_t)s * 65536, PSTR,
           Vp + (size_t)s * 262144, VPSTR, 1024, m,
           rt * 128, ct * 64, slice * 32,
           Vp + (size_t)slice * VPSTR + (size_t)s * 262144, 1024, m, m);
  } else if (blk < b1) {
    wtilde_task(wstart + (blk - b0), smem, wre, wim, epart_c, wt_re, wt_im);
  } else if (blk < b2) {
    int bc = blk - b1;
    int b = bc / NC, c = bc % NC;
    float* xs = smem;
    float* red = smem + 1024;
    for (int e = 0; e < 4; ++e) {
      int tau = t + 256 * e;
      xs[tau] = x[((size_t)b * LSEQ + tau) * NC + c];
    }
    __syncthreads();
    float p = 0.f;
    for (int e = 0; e < 4; ++e) p += xs[t + 256 * e];
    float sum = block_reduce_sum(p, red);
    float mean = sum * (1.0f / LSEQ);
    float q = 0.f;
    for (int e = 0; e < 4; ++e) { float d = xs[t + 256 * e] - mean; q += d * d; }
    float sq = block_reduce_sum(q, red);
    if (t == 0) {
      means[bc] = mean;
      stdev[bc] = sqrtf(sq * (1.0f / LSEQ) + 1e-5f);
    }
  } else if (blk < b3) {
    int bb = blk - b2;           // s*32 + chunk
    int s = bb >> 5, ch = bb & 31;
    float acc = 0.f;
    const float* base = ev + (size_t)s * LSEQ * NH + (size_t)ch * 32 * NH + t;
    for (int l = 0; l < 32; ++l) acc += base[(size_t)l * NH];
    epart_w[(size_t)bb * NH + t] = acc;
  } else if (blk < b4_) {
    // V01: col0 = B, col1 = A*B (plane 0); zero planes 1..7 cols 0..1
    int v = blk - b3;            // 0..5
    int s = v >> 1, half = v & 1;
    float* bsh = smem;           // 256
    float* psh = smem + 256;     // 256
    bsh[t] = Bv[s * 256 + t];
    __syncthreads();
    int i = half * 128 + (t >> 1);
    int k2 = (t & 1) * 128;
    const float* Arow = Pc + (size_t)s * 65536 + (size_t)i * 256 + k2;
    float acc = 0.f;
    for (int kk = 0; kk < 128; ++kk) acc += Arow[kk] * bsh[k2 + kk];
    psh[t] = acc;
    __syncthreads();
    if ((t & 1) == 0) {
      int row = s * 256 + i;
      Vp[(size_t)row * 1024 + 1] = psh[t] + psh[t + 1];
      Vp[(size_t)row * 1024] = bsh[i];
    }
    for (int z = t; z < 7 * 128 * 2; z += 256) {
      int pl = 1 + (z >> 8);
      int rr2 = (z >> 1) & 127;
      int col = z & 1;
      int row = s * 256 + half * 128 + rr2;
      Vp[(size_t)pl * VPSTR + (size_t)row * 1024 + col] = 0.f;
    }
  } else if (blk < b4_ + hCount) {
    for (int e = 0; e < 4; ++e) H[t + 256 * e] = 0.0f;
    if (t < NB * 5) out[t] = b_fc[t % 5];
  }
}

// round 10: reduceV cols 0..511 (blk<768) | Z9 = wt * Q9 small GEMM (12 blocks)
__global__ __launch_bounds__(256) void k_z9red(const float* __restrict__ Vp,
                                               float* __restrict__ V,
                                               const float* __restrict__ Q9,  // 8 planes
                                               const float* __restrict__ wt_re,
                                               const float* __restrict__ wt_im,
                                               float* __restrict__ z9r,
                                               float* __restrict__ z9i) {
  __shared__ float smem[8448];   // Bs2 64x68 (4352) + Asr 2048 + Asi 2048
  const int blk = blockIdx.x;
  const int t = threadIdx.x;
  if (blk < 768) {
    for (int e = 0; e < 2; ++e) {
      size_t idx = (size_t)blk * 1024 + e * 256 + t;
      float v = 0.f;
      #pragma unroll
      for (int pl = 0; pl < NPL; ++pl) v += Vp[(size_t)pl * VPSTR + idx];
      V[idx] = v;
    }
    return;
  }
  int zid = blk - 768;           // 0..11
  int s = zid >> 2, ct = zid & 3;
  float* Bs2 = smem;             // [64][68]
  float* Asr = smem + 4352;     // [32][64]
  float* Asi = smem + 6400;     // [32][64]
  const float* Qs = Q9 + (size_t)s * 65536;
  const int k = t & 31, cg = t >> 5;
  float accR[8], accI[8];
  #pragma unroll
  for (int j = 0; j < 8; ++j) { accR[j] = 0.f; accI[j] = 0.f; }
  for (int kb = 0; kb < 256; kb += 64) {
    for (int z = t; z < 4096; z += 256) {
      int row = z >> 6, col = z & 63;
      float v = 0.f;
      #pragma unroll
      for (int pp = 0; pp < NPL; ++pp)
        v += Qs[(size_t)pp * PSTR + (size_t)(kb + row) * 256 + ct * 64 + col];
      Bs2[row * 68 + col] = v;
    }
    for (int z = t; z < 2048; z += 256) {
      int k2 = z & 31, kk = z >> 5;
      Asr[k2 * 64 + kk] = wt_re[(size_t)(s * 32 + k2) * 256 + kb + kk];
      Asi[k2 * 64 + kk] = wt_im[(size_t)(s * 32 + k2) * 256 + kb + kk];
    }
    __syncthreads();
    for (int kk = 0; kk < 64; ++kk) {
      float ar_ = Asr[k * 64 + kk], ai_ = Asi[k * 64 + kk];
      #pragma unroll
      for (int j = 0; j < 8; ++j) {
        float b = Bs2[kk * 68 + cg * 8 + j];
        accR[j] += ar_ * b; accI[j] += ai_ * b;
      }
    }
    __syncthreads();
  }
  #pragma unroll
  for (int j = 0; j < 8; ++j) {
    size_t o = (size_t)(s * 32 + k) * 256 + ct * 64 + cg * 8 + j;
    z9r[o] = accR[j];
    z9i[o] = accI[j];
  }
}

// fused: ut row (s,k) -> twiddle -> scan -> atomic H contribution.
// d < 512: ut = wt . V[:,d]; d >= 512: ut = z9 . V[:,d-512]
__global__ __launch_bounds__(256) void k_utscan(const float* __restrict__ wt_re,
                                                const float* __restrict__ wt_im,
                                                const float* __restrict__ z9r,
                                                const float* __restrict__ z9i,
                                                const float* __restrict__ V,
                                                const float* __restrict__ w_mlp,
                                                float* __restrict__ H) {
  int blk = blockIdx.x;   // s*NM + k
  int s = blk / NM, k = blk & 31;
  int t = threadIdx.x;
  __shared__ float sr[LSEQ], si_[LSEQ];
  __shared__ float cr[256], ci[256];
  __shared__ float wsm[1024];  // [0:256)=wtr [256:512)=zr [512:768)=wti [768:1024)=zi
  wsm[t]        = wt_re[(size_t)blk * NH + t];
  wsm[256 + t]  = z9r[(size_t)blk * NH + t];
  wsm[512 + t]  = wt_im[(size_t)blk * NH + t];
  wsm[768 + t]  = z9i[(size_t)blk * NH + t];
  __syncthreads();
  const float* Vs = V + (size_t)s * NH * LSEQ;
  const int off = (t >> 7) << 8;       // 0 for d<512, 256 for d>=512
  const int col4 = (4 * t) & 511;
  float ar[4] = {0.f, 0.f, 0.f, 0.f}, ai[4] = {0.f, 0.f, 0.f, 0.f};
  for (int i = 0; i < NH; ++i) {
    float a = wsm[off + i];
    float b = wsm[512 + off + i];
    float4 v4 = *(const float4*)(Vs + (size_t)i * LSEQ + col4);
    ar[0] += a * v4.x; ai[0] += b * v4.x;
    ar[1] += a * v4.y; ai[1] += b * v4.y;
    ar[2] += a * v4.z; ai[2] += b * v4.z;
    ar[3] += a * v4.w; ai[3] += b * v4.w;
  }
  // twiddle + local serial scan in registers (d = 4t+e)
  float lr[4], li[4], rr = 0.f, ii = 0.f;
  #pragma unroll
  for (int e = 0; e < 4; ++e) {
    int d = 4 * t + e;
    int frac = (k * d) & 1023;
    float ang = -(TWO_PI / 1024.0f) * (float)frac;
    float sn, csn; sincosf(ang, &sn, &csn);
    float tr = ar[e] * csn - ai[e] * sn;
    float ti = ar[e] * sn + ai[e] * csn;
    rr += tr; ii += ti;
    lr[e] = rr; li[e] = ii;
  }
  cr[t] = rr; ci[t] = ii;
  __syncthreads();
  for (int off2 = 1; off2 < 256; off2 <<= 1) {
    float pr = 0.f, pi = 0.f;
    if (t >= off2) { pr = cr[t - off2]; pi = ci[t - off2]; }
    __syncthreads();
    cr[t] += pr; ci[t] += pi;
    __syncthreads();
  }
  float offr = (t > 0) ? cr[t - 1] : 0.0f;
  float offi = (t > 0) ? ci[t - 1] : 0.0f;
  #pragma unroll
  for (int e = 0; e < 4; ++e) {
    sr[4 * t + e] = lr[e] + offr;
    si_[4 * t + e] = li[e] + offi;
  }
  __syncthreads();
  float wm = w_mlp[s];
  float coef = wm * ((k == 0) ? 1.0f : 2.0f) * (1.0f / LSEQ);
  for (int e = 0; e < 4; ++e) {
    int tau = t + 256 * e;
    int mIdx = 1023 - tau;
    int frac = (k * (tau + 1)) & 1023;
    float ang = -(TWO_PI / 1024.0f) * (float)frac;
    float sn, csn; sincosf(ang, &sn, &csn);
    float val = coef * (sr[mIdx] * csn - si_[mIdx] * sn);
    atomicAdd(&H[tau], val);
  }
}

// feat per (b,c) + atomic accumulate into out (pre-initialized to b_fc)
__global__ __launch_bounds__(256) void k_feat(const float* __restrict__ x,
                                              const float* __restrict__ means,
                                              const float* __restrict__ stdev,
                                              const float* __restrict__ aw,
                                              const float* __restrict__ ab,
                                              const float* __restrict__ b_mlp,
                                              const float* __restrict__ H,
                                              const float* __restrict__ w_fc,
                                              float* __restrict__ out) {
  int bc = blockIdx.x; int b = bc / NC, c = bc % NC;
  __shared__ float red[256];
  int t = threadIdx.x;
  float mn = means[bc], sd = stdev[bc];
  float w = aw[c], bb = ab[c];
  float acc = 0.f;
  for (int e = 0; e < 4; ++e) {
    int tau = t + 256 * e;
    float xv = x[((size_t)b * LSEQ + tau) * NC + c];
    float f = (xv - mn) / sd * w + bb;
    acc += f * H[tau];
  }
  float sum = block_reduce_sum(acc, red);
  if (t == 0) {
    float mr = sum + b_mlp[0];
    float featv = (mr - bb) / (w + 1e-10f) * sd + mn;
    #pragma unroll
    for (int d = 0; d < 5; ++d)
      atomicAdd(&out[b * 5 + d], featv * w_fc[d * NC + c]);
  }
}

extern "C" void kernel_launch(void* const* d_in, const int* in_sizes, int n_in,
                              void* d_out, int out_size, void* d_ws, size_t ws_size,
                              hipStream_t stream) {
  const float* x_enc   = (const float*)d_in[0];
  const float* aw      = (const float*)d_in[1];
  const float* ab      = (const float*)d_in[2];
  const float* wre     = (const float*)d_in[3];
  const float* wim     = (const float*)d_in[4];
  const float* w_mlp   = (const float*)d_in[5];
  const float* b_mlp   = (const float*)d_in[6];
  const float* w_fc    = (const float*)d_in[7];
  const float* b_fc    = (const float*)d_in[8];
  const float* A_mats  = (const float*)d_in[9];
  const float* B_vecs  = (const float*)d_in[10];
  const float* ev      = (const float*)d_in[11];

  float* ws    = (float*)d_ws;
  float* means = ws + OFF_MEANS;
  float* stdev = ws + OFF_STDEV;
  float* epart = ws + OFF_EPART;
  float* wt_re = ws + OFF_WT_RE;
  float* wt_im = ws + OFF_WT_IM;
  float* Vp    = ws + OFF_VP;
  float* V     = ws + OFF_V;
  float* PP0   = ws + OFF_PP0;
  float* PP1   = ws + OFF_PP1;
  float* H     = ws + OFF_H;
  float* z9r   = ws + OFF_Z9R;
  float* z9i   = ws + OFF_Z9I;
  float* out   = (float*)d_out;

  static const int wcn[5] = {154, 154, 154, 154, 152};
  static const int wst[5] = {0, 154, 308, 462, 616};
  const float* Pc = A_mats;
  float* Pn = PP0;
  for (int si = 0; si < 9; ++si) {
    int m = 1 << si;
    int nSq = 192;
    int ntct = (si == 0) ? 0 : ((m + 63) >> 6);
    int wstart = (si >= 1 && si <= 5) ? wst[si - 1] : 0;
    int wcount = (si >= 1 && si <= 5) ? wcn[si - 1] : 0;
    int statCount = (si == 0) ? 192 : 0;
    int epCount = (si == 0) ? 96 : 0;
    int v01Count = (si == 0) ? 6 : 0;
    int hCount = (si == 0) ? 1 : 0;
    int grid = nSq + 48 * ntct + wcount + statCount + epCount + v01Count + hCount;
    if (si == 0)
      k_chain<1><<<grid, 256, 0, stream>>>(Pc, Pn, Vp, m, nSq, ntct,
          wre, wim, epart, wt_re, wt_im, wstart, wcount,
          x_enc, means, stdev, statCount,
          ev, epart, epCount, B_vecs, v01Count, b_fc, H, out, hCount);
    else
      k_chain<NPL><<<grid, 256, 0, stream>>>(Pc, Pn, Vp, m, nSq, ntct,
          wre, wim, epart, wt_re, wt_im, wstart, wcount,
          x_enc, means, stdev, statCount,
          ev, epart, epCount, B_vecs, v01Count, b_fc, H, out, hCount);
    Pc = Pn; Pn = (Pn == PP0) ? PP1 : PP0;
  }

  // round 10: reduceV (cols 0..511) + Z9 = wt * Q9
  k_z9red<<<780, 256, 0, stream>>>(Vp, V, Pc, wt_re, wt_im, z9r, z9i);
  k_utscan<<<NS * NM, 256, 0, stream>>>(wt_re, wt_im, z9r, z9i, V, w_mlp, H);
  k_feat<<<192, 256, 0, stream>>>(x_enc, means, stdev, aw, ab, b_mlp, H, w_fc, out);
}

// Round 13
// 168.360 us; speedup vs baseline: 1.1068x; 1.1068x over previous
//
#include <hip/hip_runtime.h>
#include <math.h>

#define LSEQ 1024
#define NB 16
#define NC 12
#define NH 256
#define NM 32
#define NS 3
#define TWO_PI 6.283185307179586f

#define NPL   8          // split-K planes
#define PSTR  196608     // P plane stride (3*256*256)
#define VPSTR 786432     // V plane stride (3*256*1024)

// ---- workspace layout (float offsets) ----
#define OFF_MEANS 0            // 192
#define OFF_STDEV 192          // 192
#define OFF_EPART 384          // 24576
#define OFF_WT_RE 24960        // 24576
#define OFF_WT_IM 49536        // 24576
#define OFF_VP    74112        // 8 planes x 786432 = 6291456
#define OFF_V     6365568      // 786432 (dense; only cols 0..511 used)
#define OFF_PP0   7152000      // 8 planes x 196608 = 1572864
#define OFF_PP1   8724864      // 1572864
#define OFF_H     10297728     // 1024
#define OFF_Z9R   10298752     // 24576
#define OFF_Z9I   10323328     // 24576

__device__ __forceinline__ float block_reduce_sum(float v, float* sbuf) {
  int t = threadIdx.x;
  sbuf[t] = v; __syncthreads();
  for (int off = 128; off > 0; off >>= 1) {
    if (t < off) sbuf[t] += sbuf[t + off];
    __syncthreads();
  }
  float r = sbuf[0];
  __syncthreads();
  return r;
}

// float4 wtilde task for one (s,i): wt[s,k,i] = sum_o ebar[s,o]*w[s,i,o,k]
__device__ __forceinline__ void wtilde_task(int w, float* smem,
                                            const float* __restrict__ wre,
                                            const float* __restrict__ wim,
                                            const float* __restrict__ epart,
                                            float* __restrict__ wt_re,
                                            float* __restrict__ wt_im) {
  int s = w >> 8, i = w & 255;
  int t = threadIdx.x;
  float* ebs = smem;
  float* sr  = smem + 256;
  float* si2 = smem + 1280;
  float eb = 0.f;
  for (int ch = 0; ch < 32; ++ch) eb += epart[(s * 32 + ch) * 256 + t];
  ebs[t] = eb * (1.0f / LSEQ);
  __syncthreads();
  const float* br = wre + (size_t)(s * NH + i) * NH * NM;
  const float* bi = wim + (size_t)(s * NH + i) * NH * NM;
  float aR[4] = {0.f, 0.f, 0.f, 0.f}, aI[4] = {0.f, 0.f, 0.f, 0.f};
  #pragma unroll
  for (int it = 0; it < 8; ++it) {
    int o = (t >> 3) + 32 * it;
    float e = ebs[o];
    float4 vr = *(const float4*)(br + (size_t)t * 4 + 1024 * it);
    float4 vi = *(const float4*)(bi + (size_t)t * 4 + 1024 * it);
    aR[0] += e * vr.x; aR[1] += e * vr.y; aR[2] += e * vr.z; aR[3] += e * vr.w;
    aI[0] += e * vi.x; aI[1] += e * vi.y; aI[2] += e * vi.z; aI[3] += e * vi.w;
  }
  *(float4*)(sr + t * 4)  = make_float4(aR[0], aR[1], aR[2], aR[3]);
  *(float4*)(si2 + t * 4) = make_float4(aI[0], aI[1], aI[2], aI[3]);
  __syncthreads();
  if (t < 32) {
    float r = 0.f, im = 0.f;
    #pragma unroll
    for (int og = 0; og < 32; ++og) { r += sr[og * 32 + t]; im += si2[og * 32 + t]; }
    wt_re[(size_t)(s * NM + t) * NH + i] = r;
    wt_im[(size_t)(s * NM + t) * NH + i] = im;
  }
  __syncthreads();
}

#define FMA_ROW(r, av) { acc[r][0] += (av)*b4.x; acc[r][1] += (av)*b4.y; acc[r][2] += (av)*b4.z; acc[r][3] += (av)*b4.w; }

// 128x64 output tile, single K-slice of 32 (one barrier round). 8x4 acc/thread.
template<int ANP, int BNP>
__device__ __forceinline__ void gemm32(float* As, float* Bs,
                       const float* Abase, int apstr,
                       const float* Bbase, int bpstr, int bld, int colLimit,
                       int rowbase, int colbase, int kb,
                       float* outp, int outld, int outcol0, int outColLim) {
  const int tid = threadIdx.x;
  const int tx = tid & 15, ty = tid >> 4;
  const int kkA = tid & 31, rA = tid >> 5;
  const int jB = tid & 63, kB = tid >> 6;
  float acc[8][4];
  #pragma unroll
  for (int i = 0; i < 8; ++i)
    #pragma unroll
    for (int j = 0; j < 4; ++j) acc[i][j] = 0.f;

  #pragma unroll
  for (int p = 0; p < 16; ++p) {
    int row = rowbase + rA + 8 * p;
    float pv[ANP];
    #pragma unroll
    for (int pp = 0; pp < ANP; ++pp)
      pv[pp] = Abase[(size_t)pp * apstr + (size_t)row * 256 + kb + kkA];
    float v = pv[0];
    #pragma unroll
    for (int pp = 1; pp < ANP; ++pp) v += pv[pp];
    As[kkA * 132 + rA + 8 * p] = v;
  }
  #pragma unroll
  for (int q = 0; q < 8; ++q) {
    int kk = kB + 4 * q;
    int j = colbase + jB;
    float v = 0.f;
    if (j < colLimit) {
      float pv[BNP];
      #pragma unroll
      for (int pp = 0; pp < BNP; ++pp)
        pv[pp] = Bbase[(size_t)pp * bpstr + (size_t)(kb + kk) * bld + j];
      v = pv[0];
      #pragma unroll
      for (int pp = 1; pp < BNP; ++pp) v += pv[pp];
    }
    Bs[kk * 68 + jB] = v;
  }
  __syncthreads();
  #pragma unroll
  for (int kk = 0; kk < 32; ++kk) {
    float4 b4 = *(const float4*)(Bs + kk * 68 + tx * 4);
    float4 a0 = *(const float4*)(As + kk * 132 + ty * 8);
    float4 a1 = *(const float4*)(As + kk * 132 + ty * 8 + 4);
    FMA_ROW(0, a0.x) FMA_ROW(1, a0.y) FMA_ROW(2, a0.z) FMA_ROW(3, a0.w)
    FMA_ROW(4, a1.x) FMA_ROW(5, a1.y) FMA_ROW(6, a1.z) FMA_ROW(7, a1.w)
  }
  __syncthreads();
  if (colbase + 64 <= outColLim) {
    #pragma unroll
    for (int i = 0; i < 8; ++i) {
      int row = rowbase + ty * 8 + i;
      float4 st; st.x = acc[i][0]; st.y = acc[i][1]; st.z = acc[i][2]; st.w = acc[i][3];
      *(float4*)(outp + (size_t)row * outld + outcol0 + colbase + tx * 4) = st;
    }
  } else {
    #pragma unroll
    for (int i = 0; i < 8; ++i) {
      int row = rowbase + ty * 8 + i;
      #pragma unroll
      for (int j = 0; j < 4; ++j) {
        int c = colbase + tx * 4 + j;
        if (c < outColLim) outp[(size_t)row * outld + outcol0 + c] = acc[i][j];
      }
    }
  }
}

// chain stage: squares | extends | wtilde | stats | epart | V01 | H/out init
template<int ANP>
__global__ __launch_bounds__(256) void k_chain(const float* __restrict__ Pc,
                                               float* __restrict__ Pn,
                                               float* __restrict__ Vp,
                                               int m, int nSq, int ntct,
                                               const float* __restrict__ wre,
                                               const float* __restrict__ wim,
                                               const float* __restrict__ epart_c,
                                               float* __restrict__ wt_re,
                                               float* __restrict__ wt_im,
                                               int wstart, int wcount,
                                               const float* __restrict__ x,
                                               float* __restrict__ means,
                                               float* __restrict__ stdev,
                                               int statCount,
                                               const float* __restrict__ ev,
                                               float* __restrict__ epart_w,
                                               int epCount,
                                               const float* __restrict__ Bv,
                                               int v01Count,
                                               const float* __restrict__ b_fc,
                                               float* __restrict__ H,
                                               float* __restrict__ out,
                                               int hCount) {
  __shared__ float smem[6608];
  float* As = smem;            // [32][132]
  float* Bs = smem + 4224;     // [32][68]
  const int blk = blockIdx.x;
  const int t = threadIdx.x;
  const int nExt = 48 * ntct;
  const int b0 = nSq + nExt;
  const int b1 = b0 + wcount;
  const int b2 = b1 + statCount;
  const int b3 = b2 + epCount;
  const int b4_ = b3 + v01Count;
  if (blk < nSq) {
    int slice = blk & 7, rest = blk >> 3;
    int t8 = rest & 7, s = rest >> 3;
    int rt = t8 & 1, ct = t8 >> 1;
    const float* Ab = Pc + (size_t)s * 65536;
    gemm32<ANP, ANP>(As, Bs, Ab, PSTR, Ab, PSTR, 256, 256,
           rt * 128, ct * 64, slice * 32,
           Pn + (size_t)slice * PSTR + (size_t)s * 65536, 256, 0, 256);
  } else if (blk < b0) {
    int e = blk - nSq;
    int slice = e & 7, rt = (e >> 3) & 1, rest2 = e >> 4;
    int ct = rest2 % ntct, s = rest2 / ntct;
    gemm32<ANP, NPL>(As, Bs, Pc + (size_t)s * 65536, PSTR,
           Vp + (size_t)s * 262144, VPSTR, 1024, m,
           rt * 128, ct * 64, slice * 32,
           Vp + (size_t)slice * VPSTR + (size_t)s * 262144, 1024, m, m);
  } else if (blk < b1) {
    wtilde_task(wstart + (blk - b0), smem, wre, wim, epart_c, wt_re, wt_im);
  } else if (blk < b2) {
    int bc = blk - b1;
    int b = bc / NC, c = bc % NC;
    float* xs = smem;
    float* red = smem + 1024;
    for (int e = 0; e < 4; ++e) {
      int tau = t + 256 * e;
      xs[tau] = x[((size_t)b * LSEQ + tau) * NC + c];
    }
    __syncthreads();
    float p = 0.f;
    for (int e = 0; e < 4; ++e) p += xs[t + 256 * e];
    float sum = block_reduce_sum(p, red);
    float mean = sum * (1.0f / LSEQ);
    float q = 0.f;
    for (int e = 0; e < 4; ++e) { float d = xs[t + 256 * e] - mean; q += d * d; }
    float sq = block_reduce_sum(q, red);
    if (t == 0) {
      means[bc] = mean;
      stdev[bc] = sqrtf(sq * (1.0f / LSEQ) + 1e-5f);
    }
  } else if (blk < b3) {
    int bb = blk - b2;           // s*32 + chunk
    int s = bb >> 5, ch = bb & 31;
    float acc = 0.f;
    const float* base = ev + (size_t)s * LSEQ * NH + (size_t)ch * 32 * NH + t;
    for (int l = 0; l < 32; ++l) acc += base[(size_t)l * NH];
    epart_w[(size_t)bb * NH + t] = acc;
  } else if (blk < b4_) {
    // V01: col0 = B, col1 = A*B (plane 0); zero planes 1..7 cols 0..1
    int v = blk - b3;            // 0..5
    int s = v >> 1, half = v & 1;
    float* bsh = smem;           // 256
    float* psh = smem + 256;     // 256
    bsh[t] = Bv[s * 256 + t];
    __syncthreads();
    int i = half * 128 + (t >> 1);
    int k2 = (t & 1) * 128;
    const float* Arow = Pc + (size_t)s * 65536 + (size_t)i * 256 + k2;
    float acc = 0.f;
    for (int kk = 0; kk < 128; ++kk) acc += Arow[kk] * bsh[k2 + kk];
    psh[t] = acc;
    __syncthreads();
    if ((t & 1) == 0) {
      int row = s * 256 + i;
      Vp[(size_t)row * 1024 + 1] = psh[t] + psh[t + 1];
      Vp[(size_t)row * 1024] = bsh[i];
    }
    for (int z = t; z < 7 * 128 * 2; z += 256) {
      int pl = 1 + (z >> 8);
      int rr2 = (z >> 1) & 127;
      int col = z & 1;
      int row = s * 256 + half * 128 + rr2;
      Vp[(size_t)pl * VPSTR + (size_t)row * 1024 + col] = 0.f;
    }
  } else if (blk < b4_ + hCount) {
    for (int e = 0; e < 4; ++e) H[t + 256 * e] = 0.0f;
    if (t < NB * 5) out[t] = b_fc[t % 5];
  }
}

// round 10: reduceV cols 0..511 float4 (blk<768) | Z9 = wt * Q9 (24 blocks, conflict-free)
__global__ __launch_bounds__(256) void k_z9red(const float* __restrict__ Vp,
                                               float* __restrict__ V,
                                               const float* __restrict__ Q9,  // 8 planes
                                               const float* __restrict__ wt_re,
                                               const float* __restrict__ wt_im,
                                               float* __restrict__ z9r,
                                               float* __restrict__ z9i) {
  __shared__ float smem[6608];   // Bs2 64x36 (2304) + Asr 64x33 (2112) + Asi 2112
  const int blk = blockIdx.x;
  const int t = threadIdx.x;
  if (blk < 768) {
    if (t < 128) {
      size_t idx = (size_t)blk * 1024 + t * 4;
      float4 a = *(const float4*)(Vp + idx);
      #pragma unroll
      for (int pl = 1; pl < NPL; ++pl) {
        float4 u = *(const float4*)(Vp + (size_t)pl * VPSTR + idx);
        a.x += u.x; a.y += u.y; a.z += u.z; a.w += u.w;
      }
      *(float4*)(V + idx) = a;
    }
    return;
  }
  int zid = blk - 768;           // 0..23
  int s = zid >> 3, ct = zid & 7;  // 32-col tile
  float* Bs2 = smem;             // [64][36]
  float* Asr = smem + 2304;      // [64][33] transposed: [kk][k]
  float* Asi = smem + 4416;      // [64][33]
  const float* Qs = Q9 + (size_t)s * 65536;
  const int k = t & 31, cg = t >> 5;   // cg 0..7, 4 cols each
  float accR[4] = {0.f, 0.f, 0.f, 0.f}, accI[4] = {0.f, 0.f, 0.f, 0.f};
  for (int kb = 0; kb < 256; kb += 64) {
    // Bs2: 64 rows x 32 cols, 8-plane sum, float4 (512 slots)
    for (int z = t; z < 512; z += 256) {
      int row = z >> 3, c4 = (z & 7) * 4;
      const float* qb = Qs + (size_t)(kb + row) * 256 + ct * 32 + c4;
      float4 a = *(const float4*)(qb);
      #pragma unroll
      for (int pp = 1; pp < NPL; ++pp) {
        float4 u = *(const float4*)(qb + (size_t)pp * PSTR);
        a.x += u.x; a.y += u.y; a.z += u.z; a.w += u.w;
      }
      *(float4*)(Bs2 + row * 36 + c4) = a;
    }
    // Asr/Asi transposed [kk][k] with pad 33; global reads coalesced over kk
    for (int z = t; z < 2048; z += 256) {
      int k2 = z >> 6, kk = z & 63;
      Asr[kk * 33 + k2] = wt_re[(size_t)(s * 32 + k2) * 256 + kb + kk];
      Asi[kk * 33 + k2] = wt_im[(size_t)(s * 32 + k2) * 256 + kb + kk];
    }
    __syncthreads();
    for (int kk = 0; kk < 64; ++kk) {
      float ar_ = Asr[kk * 33 + k];
      float ai_ = Asi[kk * 33 + k];
      #pragma unroll
      for (int j = 0; j < 4; ++j) {
        float b = Bs2[kk * 36 + cg * 4 + j];
        accR[j] += ar_ * b; accI[j] += ai_ * b;
      }
    }
    __syncthreads();
  }
  size_t o = (size_t)(s * 32 + k) * 256 + ct * 32 + cg * 4;
  *(float4*)(z9r + o) = make_float4(accR[0], accR[1], accR[2], accR[3]);
  *(float4*)(z9i + o) = make_float4(accI[0], accI[1], accI[2], accI[3]);
}

// fused: ut row (s,k) -> twiddle -> scan -> atomic H contribution.
// d < 512: ut = wt . V[:,d]; d >= 512: ut = z9 . V[:,d-512]
__global__ __launch_bounds__(256) void k_utscan(const float* __restrict__ wt_re,
                                                const float* __restrict__ wt_im,
                                                const float* __restrict__ z9r,
                                                const float* __restrict__ z9i,
                                                const float* __restrict__ V,
                                                const float* __restrict__ w_mlp,
                                                float* __restrict__ H) {
  int blk = blockIdx.x;   // s*NM + k
  int s = blk / NM, k = blk & 31;
  int t = threadIdx.x;
  __shared__ float sr[LSEQ], si_[LSEQ];
  __shared__ float cr[256], ci[256];
  __shared__ float wsm[1024];  // [0:256)=wtr [256:512)=zr [512:768)=wti [768:1024)=zi
  wsm[t]        = wt_re[(size_t)blk * NH + t];
  wsm[256 + t]  = z9r[(size_t)blk * NH + t];
  wsm[512 + t]  = wt_im[(size_t)blk * NH + t];
  wsm[768 + t]  = z9i[(size_t)blk * NH + t];
  __syncthreads();
  const float* Vs = V + (size_t)s * NH * LSEQ;
  const int off = (t >> 7) << 8;       // 0 for d<512, 256 for d>=512
  const int col4 = (4 * t) & 511;
  float ar[4] = {0.f, 0.f, 0.f, 0.f}, ai[4] = {0.f, 0.f, 0.f, 0.f};
  for (int i = 0; i < NH; ++i) {
    float a = wsm[off + i];
    float b = wsm[512 + off + i];
    float4 v4 = *(const float4*)(Vs + (size_t)i * LSEQ + col4);
    ar[0] += a * v4.x; ai[0] += b * v4.x;
    ar[1] += a * v4.y; ai[1] += b * v4.y;
    ar[2] += a * v4.z; ai[2] += b * v4.z;
    ar[3] += a * v4.w; ai[3] += b * v4.w;
  }
  // twiddle + local serial scan in registers (d = 4t+e)
  float lr[4], li[4], rr = 0.f, ii = 0.f;
  #pragma unroll
  for (int e = 0; e < 4; ++e) {
    int d = 4 * t + e;
    int frac = (k * d) & 1023;
    float ang = -(TWO_PI / 1024.0f) * (float)frac;
    float sn, csn; sincosf(ang, &sn, &csn);
    float tr = ar[e] * csn - ai[e] * sn;
    float ti = ar[e] * sn + ai[e] * csn;
    rr += tr; ii += ti;
    lr[e] = rr; li[e] = ii;
  }
  cr[t] = rr; ci[t] = ii;
  __syncthreads();
  for (int off2 = 1; off2 < 256; off2 <<= 1) {
    float pr = 0.f, pi = 0.f;
    if (t >= off2) { pr = cr[t - off2]; pi = ci[t - off2]; }
    __syncthreads();
    cr[t] += pr; ci[t] += pi;
    __syncthreads();
  }
  float offr = (t > 0) ? cr[t - 1] : 0.0f;
  float offi = (t > 0) ? ci[t - 1] : 0.0f;
  #pragma unroll
  for (int e = 0; e < 4; ++e) {
    sr[4 * t + e] = lr[e] + offr;
    si_[4 * t + e] = li[e] + offi;
  }
  __syncthreads();
  float wm = w_mlp[s];
  float coef = wm * ((k == 0) ? 1.0f : 2.0f) * (1.0f / LSEQ);
  for (int e = 0; e < 4; ++e) {
    int tau = t + 256 * e;
    int mIdx = 1023 - tau;
    int frac = (k * (tau + 1)) & 1023;
    float ang = -(TWO_PI / 1024.0f) * (float)frac;
    float sn, csn; sincosf(ang, &sn, &csn);
    float val = coef * (sr[mIdx] * csn - si_[mIdx] * sn);
    atomicAdd(&H[tau], val);
  }
}

// feat per (b,c) + atomic accumulate into out (pre-initialized to b_fc)
__global__ __launch_bounds__(256) void k_feat(const float* __restrict__ x,
                                              const float* __restrict__ means,
                                              const float* __restrict__ stdev,
                                              const float* __restrict__ aw,
                                              const float* __restrict__ ab,
                                              const float* __restrict__ b_mlp,
                                              const float* __restrict__ H,
                                              const float* __restrict__ w_fc,
                                              float* __restrict__ out) {
  int bc = blockIdx.x; int b = bc / NC, c = bc % NC;
  __shared__ float red[256];
  int t = threadIdx.x;
  float mn = means[bc], sd = stdev[bc];
  float w = aw[c], bb = ab[c];
  float acc = 0.f;
  for (int e = 0; e < 4; ++e) {
    int tau = t + 256 * e;
    float xv = x[((size_t)b * LSEQ + tau) * NC + c];
    float f = (xv - mn) / sd * w + bb;
    acc += f * H[tau];
  }
  float sum = block_reduce_sum(acc, red);
  if (t == 0) {
    float mr = sum + b_mlp[0];
    float featv = (mr - bb) / (w + 1e-10f) * sd + mn;
    #pragma unroll
    for (int d = 0; d < 5; ++d)
      atomicAdd(&out[b * 5 + d], featv * w_fc[d * NC + c]);
  }
}

extern "C" void kernel_launch(void* const* d_in, const int* in_sizes, int n_in,
                              void* d_out, int out_size, void* d_ws, size_t ws_size,
                              hipStream_t stream) {
  const float* x_enc   = (const float*)d_in[0];
  const float* aw      = (const float*)d_in[1];
  const float* ab      = (const float*)d_in[2];
  const float* wre     = (const float*)d_in[3];
  const float* wim     = (const float*)d_in[4];
  const float* w_mlp   = (const float*)d_in[5];
  const float* b_mlp   = (const float*)d_in[6];
  const float* w_fc    = (const float*)d_in[7];
  const float* b_fc    = (const float*)d_in[8];
  const float* A_mats  = (const float*)d_in[9];
  const float* B_vecs  = (const float*)d_in[10];
  const float* ev      = (const float*)d_in[11];

  float* ws    = (float*)d_ws;
  float* means = ws + OFF_MEANS;
  float* stdev = ws + OFF_STDEV;
  float* epart = ws + OFF_EPART;
  float* wt_re = ws + OFF_WT_RE;
  float* wt_im = ws + OFF_WT_IM;
  float* Vp    = ws + OFF_VP;
  float* V     = ws + OFF_V;
  float* PP0   = ws + OFF_PP0;
  float* PP1   = ws + OFF_PP1;
  float* H     = ws + OFF_H;
  float* z9r   = ws + OFF_Z9R;
  float* z9i   = ws + OFF_Z9I;
  float* out   = (float*)d_out;

  static const int wcn[5] = {154, 154, 154, 154, 152};
  static const int wst[5] = {0, 154, 308, 462, 616};
  const float* Pc = A_mats;
  float* Pn = PP0;
  for (int si = 0; si < 9; ++si) {
    int m = 1 << si;
    int nSq = 192;
    int ntct = (si == 0) ? 0 : ((m + 63) >> 6);
    int wstart = (si >= 1 && si <= 5) ? wst[si - 1] : 0;
    int wcount = (si >= 1 && si <= 5) ? wcn[si - 1] : 0;
    int statCount = (si == 0) ? 192 : 0;
    int epCount = (si == 0) ? 96 : 0;
    int v01Count = (si == 0) ? 6 : 0;
    int hCount = (si == 0) ? 1 : 0;
    int grid = nSq + 48 * ntct + wcount + statCount + epCount + v01Count + hCount;
    if (si == 0)
      k_chain<1><<<grid, 256, 0, stream>>>(Pc, Pn, Vp, m, nSq, ntct,
          wre, wim, epart, wt_re, wt_im, wstart, wcount,
          x_enc, means, stdev, statCount,
          ev, epart, epCount, B_vecs, v01Count, b_fc, H, out, hCount);
    else
      k_chain<NPL><<<grid, 256, 0, stream>>>(Pc, Pn, Vp, m, nSq, ntct,
          wre, wim, epart, wt_re, wt_im, wstart, wcount,
          x_enc, means, stdev, statCount,
          ev, epart, epCount, B_vecs, v01Count, b_fc, H, out, hCount);
    Pc = Pn; Pn = (Pn == PP0) ? PP1 : PP0;
  }

  // round 10: reduceV (cols 0..511) + Z9 = wt * Q9
  k_z9red<<<792, 256, 0, stream>>>(Vp, V, Pc, wt_re, wt_im, z9r, z9i);
  k_utscan<<<NS * NM, 256, 0, stream>>>(wt_re, wt_im, z9r, z9i, V, w_mlp, H);
  k_feat<<<192, 256, 0, stream>>>(x_enc, means, stdev, aw, ab, b_mlp, H, w_fc, out);
}

// Round 14
// 161.135 us; speedup vs baseline: 1.1564x; 1.0448x over previous
//
#include <hip/hip_runtime.h>
#include <math.h>

#define LSEQ 1024
#define NB 16
#define NC 12
#define NH 256
#define NM 32
#define NS 3
#define TWO_PI 6.283185307179586f

#define NPL   8          // split-K planes
#define PSTR  196608     // P plane stride (3*256*256)
#define VPSTR 786432     // V plane stride (3*256*1024)

// ---- workspace layout (float offsets) ----
#define OFF_MEANS 0            // 192
#define OFF_STDEV 192          // 192
#define OFF_EPART 384          // 24576
#define OFF_WT_RE 24960        // 24576
#define OFF_WT_IM 49536        // 24576
#define OFF_VP    74112        // 8 planes x 786432 = 6291456
#define OFF_V     6365568      // 786432 (dense)
#define OFF_PP0   7152000      // 8 planes x 196608 = 1572864
#define OFF_PP1   8724864      // 1572864
#define OFF_H     10297728     // 1024

__device__ __forceinline__ float block_reduce_sum(float v, float* sbuf) {
  int t = threadIdx.x;
  sbuf[t] = v; __syncthreads();
  for (int off = 128; off > 0; off >>= 1) {
    if (t < off) sbuf[t] += sbuf[t + off];
    __syncthreads();
  }
  float r = sbuf[0];
  __syncthreads();
  return r;
}

// float4 wtilde task for one (s,i): wt[s,k,i] = sum_o ebar[s,o]*w[s,i,o,k]
__device__ __forceinline__ void wtilde_task(int w, float* smem,
                                            const float* __restrict__ wre,
                                            const float* __restrict__ wim,
                                            const float* __restrict__ epart,
                                            float* __restrict__ wt_re,
                                            float* __restrict__ wt_im) {
  int s = w >> 8, i = w & 255;
  int t = threadIdx.x;
  float* ebs = smem;
  float* sr  = smem + 256;
  float* si2 = smem + 1280;
  float eb = 0.f;
  for (int ch = 0; ch < 32; ++ch) eb += epart[(s * 32 + ch) * 256 + t];
  ebs[t] = eb * (1.0f / LSEQ);
  __syncthreads();
  const float* br = wre + (size_t)(s * NH + i) * NH * NM;
  const float* bi = wim + (size_t)(s * NH + i) * NH * NM;
  float aR[4] = {0.f, 0.f, 0.f, 0.f}, aI[4] = {0.f, 0.f, 0.f, 0.f};
  #pragma unroll
  for (int it = 0; it < 8; ++it) {
    int o = (t >> 3) + 32 * it;
    float e = ebs[o];
    float4 vr = *(const float4*)(br + (size_t)t * 4 + 1024 * it);
    float4 vi = *(const float4*)(bi + (size_t)t * 4 + 1024 * it);
    aR[0] += e * vr.x; aR[1] += e * vr.y; aR[2] += e * vr.z; aR[3] += e * vr.w;
    aI[0] += e * vi.x; aI[1] += e * vi.y; aI[2] += e * vi.z; aI[3] += e * vi.w;
  }
  *(float4*)(sr + t * 4)  = make_float4(aR[0], aR[1], aR[2], aR[3]);
  *(float4*)(si2 + t * 4) = make_float4(aI[0], aI[1], aI[2], aI[3]);
  __syncthreads();
  if (t < 32) {
    float r = 0.f, im = 0.f;
    #pragma unroll
    for (int og = 0; og < 32; ++og) { r += sr[og * 32 + t]; im += si2[og * 32 + t]; }
    wt_re[(size_t)(s * NM + t) * NH + i] = r;
    wt_im[(size_t)(s * NM + t) * NH + i] = im;
  }
  __syncthreads();
}

#define FMA_ROW(r, av) { acc[r][0] += (av)*b4.x; acc[r][1] += (av)*b4.y; acc[r][2] += (av)*b4.z; acc[r][3] += (av)*b4.w; }

// 128x64 output tile, single K-slice of 32 (one barrier round). 8x4 acc/thread.
template<int ANP, int BNP>
__device__ __forceinline__ void gemm32(float* As, float* Bs,
                       const float* Abase, int apstr,
                       const float* Bbase, int bpstr, int bld, int colLimit,
                       int rowbase, int colbase, int kb,
                       float* outp, int outld, int outcol0, int outColLim) {
  const int tid = threadIdx.x;
  const int tx = tid & 15, ty = tid >> 4;
  const int kkA = tid & 31, rA = tid >> 5;
  const int jB = tid & 63, kB = tid >> 6;
  float acc[8][4];
  #pragma unroll
  for (int i = 0; i < 8; ++i)
    #pragma unroll
    for (int j = 0; j < 4; ++j) acc[i][j] = 0.f;

  #pragma unroll
  for (int p = 0; p < 16; ++p) {
    int row = rowbase + rA + 8 * p;
    float pv[ANP];
    #pragma unroll
    for (int pp = 0; pp < ANP; ++pp)
      pv[pp] = Abase[(size_t)pp * apstr + (size_t)row * 256 + kb + kkA];
    float v = pv[0];
    #pragma unroll
    for (int pp = 1; pp < ANP; ++pp) v += pv[pp];
    As[kkA * 132 + rA + 8 * p] = v;
  }
  #pragma unroll
  for (int q = 0; q < 8; ++q) {
    int kk = kB + 4 * q;
    int j = colbase + jB;
    float v = 0.f;
    if (j < colLimit) {
      float pv[BNP];
      #pragma unroll
      for (int pp = 0; pp < BNP; ++pp)
        pv[pp] = Bbase[(size_t)pp * bpstr + (size_t)(kb + kk) * bld + j];
      v = pv[0];
      #pragma unroll
      for (int pp = 1; pp < BNP; ++pp) v += pv[pp];
    }
    Bs[kk * 68 + jB] = v;
  }
  __syncthreads();
  #pragma unroll
  for (int kk = 0; kk < 32; ++kk) {
    float4 b4 = *(const float4*)(Bs + kk * 68 + tx * 4);
    float4 a0 = *(const float4*)(As + kk * 132 + ty * 8);
    float4 a1 = *(const float4*)(As + kk * 132 + ty * 8 + 4);
    FMA_ROW(0, a0.x) FMA_ROW(1, a0.y) FMA_ROW(2, a0.z) FMA_ROW(3, a0.w)
    FMA_ROW(4, a1.x) FMA_ROW(5, a1.y) FMA_ROW(6, a1.z) FMA_ROW(7, a1.w)
  }
  __syncthreads();
  if (colbase + 64 <= outColLim) {
    #pragma unroll
    for (int i = 0; i < 8; ++i) {
      int row = rowbase + ty * 8 + i;
      float4 st; st.x = acc[i][0]; st.y = acc[i][1]; st.z = acc[i][2]; st.w = acc[i][3];
      *(float4*)(outp + (size_t)row * outld + outcol0 + colbase + tx * 4) = st;
    }
  } else {
    #pragma unroll
    for (int i = 0; i < 8; ++i) {
      int row = rowbase + ty * 8 + i;
      #pragma unroll
      for (int j = 0; j < 4; ++j) {
        int c = colbase + tx * 4 + j;
        if (c < outColLim) outp[(size_t)row * outld + outcol0 + c] = acc[i][j];
      }
    }
  }
}

// chain stage: squares | extends | wtilde | stats | reduceV(0..511) | epart | V01 | H/out init
template<int ANP>
__global__ __launch_bounds__(256) void k_chain(const float* __restrict__ Pc,
                                               float* __restrict__ Pn,
                                               float* __restrict__ Vp,
                                               int m, int nSq, int ntct,
                                               const float* __restrict__ wre,
                                               const float* __restrict__ wim,
                                               const float* __restrict__ epart_c,
                                               float* __restrict__ wt_re,
                                               float* __restrict__ wt_im,
                                               int wstart, int wcount,
                                               const float* __restrict__ x,
                                               float* __restrict__ means,
                                               float* __restrict__ stdev,
                                               int statCount, int redCount,
                                               float* __restrict__ V,
                                               const float* __restrict__ ev,
                                               float* __restrict__ epart_w,
                                               int epCount,
                                               const float* __restrict__ Bv,
                                               int v01Count,
                                               const float* __restrict__ b_fc,
                                               float* __restrict__ H,
                                               float* __restrict__ out,
                                               int hCount) {
  __shared__ float smem[6608];
  float* As = smem;            // [32][132]
  float* Bs = smem + 4224;     // [32][68]
  const int blk = blockIdx.x;
  const int t = threadIdx.x;
  const int nExt = 48 * ntct;
  const int b0 = nSq + nExt;
  const int b1 = b0 + wcount;
  const int b2 = b1 + statCount;
  const int b3 = b2 + redCount;
  const int b4_ = b3 + epCount;
  const int b5 = b4_ + v01Count;
  if (blk < nSq) {
    int slice = blk & 7, rest = blk >> 3;
    int t8 = rest & 7, s = rest >> 3;
    int rt = t8 & 1, ct = t8 >> 1;
    const float* Ab = Pc + (size_t)s * 65536;
    gemm32<ANP, ANP>(As, Bs, Ab, PSTR, Ab, PSTR, 256, 256,
           rt * 128, ct * 64, slice * 32,
           Pn + (size_t)slice * PSTR + (size_t)s * 65536, 256, 0, 256);
  } else if (blk < b0) {
    int e = blk - nSq;
    int slice = e & 7, rt = (e >> 3) & 1, rest2 = e >> 4;
    int ct = rest2 % ntct, s = rest2 / ntct;
    gemm32<ANP, NPL>(As, Bs, Pc + (size_t)s * 65536, PSTR,
           Vp + (size_t)s * 262144, VPSTR, 1024, m,
           rt * 128, ct * 64, slice * 32,
           Vp + (size_t)slice * VPSTR + (size_t)s * 262144, 1024, m, m);
  } else if (blk < b1) {
    wtilde_task(wstart + (blk - b0), smem, wre, wim, epart_c, wt_re, wt_im);
  } else if (blk < b2) {
    int bc = blk - b1;
    int b = bc / NC, c = bc % NC;
    float* xs = smem;
    float* red = smem + 1024;
    for (int e = 0; e < 4; ++e) {
      int tau = t + 256 * e;
      xs[tau] = x[((size_t)b * LSEQ + tau) * NC + c];
    }
    __syncthreads();
    float p = 0.f;
    for (int e = 0; e < 4; ++e) p += xs[t + 256 * e];
    float sum = block_reduce_sum(p, red);
    float mean = sum * (1.0f / LSEQ);
    float q = 0.f;
    for (int e = 0; e < 4; ++e) { float d = xs[t + 256 * e] - mean; q += d * d; }
    float sq = block_reduce_sum(q, red);
    if (t == 0) {
      means[bc] = mean;
      stdev[bc] = sqrtf(sq * (1.0f / LSEQ) + 1e-5f);
    }
  } else if (blk < b3) {
    int rid = blk - b2;   // row 0..767; cols 0..511 final after stage 8
    if (t < 128) {
      size_t idx = (size_t)rid * 1024 + t * 4;
      float4 a = *(const float4*)(Vp + idx);
      #pragma unroll
      for (int pl = 1; pl < NPL; ++pl) {
        float4 u = *(const float4*)(Vp + (size_t)pl * VPSTR + idx);
        a.x += u.x; a.y += u.y; a.z += u.z; a.w += u.w;
      }
      *(float4*)(V + idx) = a;
    }
  } else if (blk < b4_) {
    int bb = blk - b3;           // s*32 + chunk
    int s = bb >> 5, ch = bb & 31;
    float acc = 0.f;
    const float* base = ev + (size_t)s * LSEQ * NH + (size_t)ch * 32 * NH + t;
    for (int l = 0; l < 32; ++l) acc += base[(size_t)l * NH];
    epart_w[(size_t)bb * NH + t] = acc;
  } else if (blk < b5) {
    // V01: col0 = B, col1 = A*B (plane 0); zero planes 1..7 cols 0..1
    int v = blk - b4_;           // 0..5
    int s = v >> 1, half = v & 1;
    float* bsh = smem;           // 256
    float* psh = smem + 256;     // 256
    bsh[t] = Bv[s * 256 + t];
    __syncthreads();
    int i = half * 128 + (t >> 1);
    int k2 = (t & 1) * 128;
    const float* Arow = Pc + (size_t)s * 65536 + (size_t)i * 256 + k2;
    float acc = 0.f;
    for (int kk = 0; kk < 128; ++kk) acc += Arow[kk] * bsh[k2 + kk];
    psh[t] = acc;
    __syncthreads();
    if ((t & 1) == 0) {
      int row = s * 256 + i;
      Vp[(size_t)row * 1024 + 1] = psh[t] + psh[t + 1];
      Vp[(size_t)row * 1024] = bsh[i];
    }
    for (int z = t; z < 7 * 128 * 2; z += 256) {
      int pl = 1 + (z >> 8);
      int rr2 = (z >> 1) & 127;
      int col = z & 1;
      int row = s * 256 + half * 128 + rr2;
      Vp[(size_t)pl * VPSTR + (size_t)row * 1024 + col] = 0.f;
    }
  } else if (blk < b5 + hCount) {
    for (int e = 0; e < 4; ++e) H[t + 256 * e] = 0.0f;
    if (t < NB * 5) out[t] = b_fc[t % 5];
  }
}

// collapse planes for cols 512..1023 (written by stage 9), float4
__global__ __launch_bounds__(256) void k_reduceV2(const float* __restrict__ Vp,
                                                  float* __restrict__ V) {
  int t = threadIdx.x;
  if (t < 128) {
    size_t idx = (size_t)blockIdx.x * 1024 + 512 + t * 4;
    float4 a = *(const float4*)(Vp + idx);
    #pragma unroll
    for (int pl = 1; pl < NPL; ++pl) {
      float4 u = *(const float4*)(Vp + (size_t)pl * VPSTR + idx);
      a.x += u.x; a.y += u.y; a.z += u.z; a.w += u.w;
    }
    *(float4*)(V + idx) = a;
  }
}

// fused: ut row (s,k) via float4 V reads -> twiddle -> scan -> atomic H contribution
__global__ __launch_bounds__(256) void k_utscan(const float* __restrict__ wt_re,
                                                const float* __restrict__ wt_im,
                                                const float* __restrict__ V,
                                                const float* __restrict__ w_mlp,
                                                float* __restrict__ H) {
  int blk = blockIdx.x;   // s*NM + k
  int s = blk / NM, k = blk & 31;
  int t = threadIdx.x;
  __shared__ float sr[LSEQ], si_[LSEQ];
  __shared__ float cr[256], ci[256];
  const float* wr = wt_re + (size_t)blk * NH;
  const float* wi_ = wt_im + (size_t)blk * NH;
  const float* Vs = V + (size_t)s * NH * LSEQ;
  float ar[4] = {0.f, 0.f, 0.f, 0.f}, ai[4] = {0.f, 0.f, 0.f, 0.f};
  for (int i = 0; i < NH; ++i) {
    float a = wr[i], b = wi_[i];
    float4 v4 = *(const float4*)(Vs + (size_t)i * LSEQ + 4 * t);
    ar[0] += a * v4.x; ai[0] += b * v4.x;
    ar[1] += a * v4.y; ai[1] += b * v4.y;
    ar[2] += a * v4.z; ai[2] += b * v4.z;
    ar[3] += a * v4.w; ai[3] += b * v4.w;
  }
  // twiddle + local serial scan in registers (d = 4t+e)
  float lr[4], li[4], rr = 0.f, ii = 0.f;
  #pragma unroll
  for (int e = 0; e < 4; ++e) {
    int d = 4 * t + e;
    int frac = (k * d) & 1023;
    float ang = -(TWO_PI / 1024.0f) * (float)frac;
    float sn, csn; sincosf(ang, &sn, &csn);
    float tr = ar[e] * csn - ai[e] * sn;
    float ti = ar[e] * sn + ai[e] * csn;
    rr += tr; ii += ti;
    lr[e] = rr; li[e] = ii;
  }
  cr[t] = rr; ci[t] = ii;
  __syncthreads();
  for (int off = 1; off < 256; off <<= 1) {
    float pr = 0.f, pi = 0.f;
    if (t >= off) { pr = cr[t - off]; pi = ci[t - off]; }
    __syncthreads();
    cr[t] += pr; ci[t] += pi;
    __syncthreads();
  }
  float offr = (t > 0) ? cr[t - 1] : 0.0f;
  float offi = (t > 0) ? ci[t - 1] : 0.0f;
  #pragma unroll
  for (int e = 0; e < 4; ++e) {
    sr[4 * t + e] = lr[e] + offr;
    si_[4 * t + e] = li[e] + offi;
  }
  __syncthreads();
  float wm = w_mlp[s];
  float coef = wm * ((k == 0) ? 1.0f : 2.0f) * (1.0f / LSEQ);
  for (int e = 0; e < 4; ++e) {
    int tau = t + 256 * e;
    int mIdx = 1023 - tau;
    int frac = (k * (tau + 1)) & 1023;
    float ang = -(TWO_PI / 1024.0f) * (float)frac;
    float sn, csn; sincosf(ang, &sn, &csn);
    float val = coef * (sr[mIdx] * csn - si_[mIdx] * sn);
    atomicAdd(&H[tau], val);
  }
}

// feat per (b,c) + atomic accumulate into out (pre-initialized to b_fc)
__global__ __launch_bounds__(256) void k_feat(const float* __restrict__ x,
                                              const float* __restrict__ means,
                                              const float* __restrict__ stdev,
                                              const float* __restrict__ aw,
                                              const float* __restrict__ ab,
                                              const float* __restrict__ b_mlp,
                                              const float* __restrict__ H,
                                              const float* __restrict__ w_fc,
                                              float* __restrict__ out) {
  int bc = blockIdx.x; int b = bc / NC, c = bc % NC;
  __shared__ float red[256];
  int t = threadIdx.x;
  float mn = means[bc], sd = stdev[bc];
  float w = aw[c], bb = ab[c];
  float acc = 0.f;
  for (int e = 0; e < 4; ++e) {
    int tau = t + 256 * e;
    float xv = x[((size_t)b * LSEQ + tau) * NC + c];
    float f = (xv - mn) / sd * w + bb;
    acc += f * H[tau];
  }
  float sum = block_reduce_sum(acc, red);
  if (t == 0) {
    float mr = sum + b_mlp[0];
    float featv = (mr - bb) / (w + 1e-10f) * sd + mn;
    #pragma unroll
    for (int d = 0; d < 5; ++d)
      atomicAdd(&out[b * 5 + d], featv * w_fc[d * NC + c]);
  }
}

extern "C" void kernel_launch(void* const* d_in, const int* in_sizes, int n_in,
                              void* d_out, int out_size, void* d_ws, size_t ws_size,
                              hipStream_t stream) {
  const float* x_enc   = (const float*)d_in[0];
  const float* aw      = (const float*)d_in[1];
  const float* ab      = (const float*)d_in[2];
  const float* wre     = (const float*)d_in[3];
  const float* wim     = (const float*)d_in[4];
  const float* w_mlp   = (const float*)d_in[5];
  const float* b_mlp   = (const float*)d_in[6];
  const float* w_fc    = (const float*)d_in[7];
  const float* b_fc    = (const float*)d_in[8];
  const float* A_mats  = (const float*)d_in[9];
  const float* B_vecs  = (const float*)d_in[10];
  const float* ev      = (const float*)d_in[11];

  float* ws    = (float*)d_ws;
  float* means = ws + OFF_MEANS;
  float* stdev = ws + OFF_STDEV;
  float* epart = ws + OFF_EPART;
  float* wt_re = ws + OFF_WT_RE;
  float* wt_im = ws + OFF_WT_IM;
  float* Vp    = ws + OFF_VP;
  float* V     = ws + OFF_V;
  float* PP0   = ws + OFF_PP0;
  float* PP1   = ws + OFF_PP1;
  float* H     = ws + OFF_H;
  float* out   = (float*)d_out;

  static const int wcn[5] = {154, 154, 154, 154, 152};
  static const int wst[5] = {0, 154, 308, 462, 616};
  const float* Pc = A_mats;
  float* Pn = PP0;
  for (int si = 0; si < 10; ++si) {
    int m = 1 << si;
    int doSq = (si < 9);
    int nSq = doSq ? 192 : 0;
    int ntct = (si == 0) ? 0 : ((m + 63) >> 6);
    int wstart = (si >= 1 && si <= 5) ? wst[si - 1] : 0;
    int wcount = (si >= 1 && si <= 5) ? wcn[si - 1] : 0;
    int statCount = (si == 0) ? 192 : 0;
    int redCount = (si == 9) ? 768 : 0;
    int epCount = (si == 0) ? 96 : 0;
    int v01Count = (si == 0) ? 6 : 0;
    int hCount = (si == 0) ? 1 : 0;
    int grid = nSq + 48 * ntct + wcount + statCount + redCount + epCount + v01Count + hCount;
    if (si == 0)
      k_chain<1><<<grid, 256, 0, stream>>>(Pc, Pn, Vp, m, nSq, ntct,
          wre, wim, epart, wt_re, wt_im, wstart, wcount,
          x_enc, means, stdev, statCount, redCount, V,
          ev, epart, epCount, B_vecs, v01Count, b_fc, H, out, hCount);
    else
      k_chain<NPL><<<grid, 256, 0, stream>>>(Pc, Pn, Vp, m, nSq, ntct,
          wre, wim, epart, wt_re, wt_im, wstart, wcount,
          x_enc, means, stdev, statCount, redCount, V,
          ev, epart, epCount, B_vecs, v01Count, b_fc, H, out, hCount);
    if (doSq) { Pc = Pn; Pn = (Pn == PP0) ? PP1 : PP0; }
  }

  k_reduceV2<<<768, 256, 0, stream>>>(Vp, V);
  k_utscan<<<NS * NM, 256, 0, stream>>>(wt_re, wt_im, V, w_mlp, H);
  k_feat<<<192, 256, 0, stream>>>(x_enc, means, stdev, aw, ab, b_mlp, H, w_fc, out);
}